// Round 4
// baseline (259.211 us; speedup 1.0000x reference)
//
#include <hip/hip_runtime.h>

#define T_ROWS 32
#define NROWS  65536
#define CDIM   128
#define MKEYS  1024

typedef _Float16 half8 __attribute__((ext_vector_type(8)));
typedef _Float16 half4 __attribute__((ext_vector_type(4)));
typedef float    floatx4 __attribute__((ext_vector_type(4)));

union FU { float f; unsigned u; };

#define MFMA16 __builtin_amdgcn_mfma_f32_16x16x32_f16

// ---------------- Kernel A: convert keys fp32 -> fp16 in MFMA-fragment order --------
// Layout: for key k, dim d:  g=k>>4, n=k&15, f=d>>5, q8=(d&31)>>3, e=d&7
//   kh[ ((g*4+f)*64 + q8*16 + n)*8 + e ]  = (fp16) keys[k][d]
// With lane = q8*16+n, the main kernel's fragment-f load for key group g is
// kh + (g*256 + f*64 + lane)*8 : 64 lanes x 16B fully contiguous (1KB/instr).
__global__ __launch_bounds__(256) void cvt_keys_kernel(const float* __restrict__ keys,
                                                       _Float16* __restrict__ kh) {
    int i  = blockIdx.x * 256 + threadIdx.x;        // 32768 threads
    int k  = i >> 5;                                // key 0..1023
    int d0 = (i & 31) * 4;                          // dim 0,4,...,124
    float4 f4 = *(const float4*)(keys + (long)k * CDIM + d0);
    half4 hv;
    hv[0] = (_Float16)f4.x; hv[1] = (_Float16)f4.y;
    hv[2] = (_Float16)f4.z; hv[3] = (_Float16)f4.w;
    int g = k >> 4, n = k & 15;
    int f = d0 >> 5, q8 = (d0 & 31) >> 3, e = d0 & 7;
    long idx = ((long)((g * 4 + f) * 64 + q8 * 16 + n)) * 8 + e;
    *(half4*)(kh + idx) = hv;
}

// ---------------- Kernel B: fused score/argmax/rescue/gather, 32 rows/block ----------
// Single MFMA pass + branch-free per-thread top-2 (exact 2nd max).
// NEW vs R3: per-block STAGGERED chunk sweep. All blocks previously swept the same
// 256KB key buffer in the same order in lockstep -> same-address convoying in the
// per-XCD L2 (banks serialize identical requests from ~1024 waves). Block b now
// starts at chunk (b>>3)&15 (>>3 so consecutive same-XCD blocks under round-robin
// dispatch get consecutive offsets), spreading concurrent reads across all 16
// windows of the key buffer within each XCD's L2. Top-2/threshold math is
// order-independent; ties resolved by P7's (score, lowest-key) encoding.
__global__ __launch_bounds__(256, 4) void gather_main(
    const float* __restrict__ q,      // trend_representation (65536x128)
    const float* __restrict__ rep,    // representation
    const float* __restrict__ keys,   // fp32 keys (1024x128)
    const float* __restrict__ vals,   // fp32 values
    const _Float16* __restrict__ kh,  // fp16 keys, fragment order (ws)
    float* __restrict__ out)          // [131072]: keys_g then values_g
{
    __shared__ _Float16 qh[T_ROWS][128];          // fp16 q, swizzled (8 KB)
    __shared__ float qss[T_ROWS][17];             // per-(row,c8) sumsq, padded
    __shared__ float wm1[4][T_ROWS];
    __shared__ int   wi1[4][T_ROWS];
    __shared__ float rowT[T_ROWS];
    __shared__ int   rowI1s[T_ROWS];
    __shared__ int   candCnt[T_ROWS];
    __shared__ int   candKey[T_ROWS][8];
    __shared__ int   rowOvf[T_ROWS];
    __shared__ unsigned long long rowBest[T_ROWS];
    __shared__ int   rowIdx[T_ROWS];
    __shared__ float kgp[T_ROWS][17], vgp[T_ROWS][17];

    const int t    = threadIdx.x;
    const int wid  = t >> 6;
    const int lane = t & 63;
    const int n    = lane & 15;       // A: key-in-16, B/C: q-row (col) in 16
    const int quad = lane >> 4;       // k-chunk selector / C row group
    const long g0  = (long)blockIdx.x * T_ROWS;

    if (t < T_ROWS) { candCnt[t] = 0; rowOvf[t] = 0; rowBest[t] = 0ull; }

    // ---- P1: stage q tile -> fp16 LDS (swizzled), per-(row,chunk) sumsq ----
    {
        int row = t >> 4, c8 = t & 15;
        #pragma unroll
        for (int h = 0; h < 2; ++h) {
            int rr = row + h * 16;
            const float4* src = (const float4*)(q + (g0 + rr) * CDIM + c8 * 8);
            float4 a0 = src[0], a1 = src[1];
            qss[rr][c8] = a0.x*a0.x + a0.y*a0.y + a0.z*a0.z + a0.w*a0.w
                        + a1.x*a1.x + a1.y*a1.y + a1.z*a1.z + a1.w*a1.w;
            half8 hv;
            hv[0] = (_Float16)a0.x; hv[1] = (_Float16)a0.y;
            hv[2] = (_Float16)a0.z; hv[3] = (_Float16)a0.w;
            hv[4] = (_Float16)a1.x; hv[5] = (_Float16)a1.y;
            hv[6] = (_Float16)a1.z; hv[7] = (_Float16)a1.w;
            int phys = c8 ^ (rr & 7);
            *(half8*)&qh[rr][phys * 8] = hv;
        }
    }
    __syncthreads();

    // ---- P2: hoist B-fragments (q rows n and 16+n) into registers ----
    half8 qa0, qa1, qa2, qa3, qb0, qb1, qb2, qb3;
    {
        int x = n & 7;
        qa0 = *(const half8*)&qh[n][((0 * 4 + quad) ^ x) * 8];
        qa1 = *(const half8*)&qh[n][((1 * 4 + quad) ^ x) * 8];
        qa2 = *(const half8*)&qh[n][((2 * 4 + quad) ^ x) * 8];
        qa3 = *(const half8*)&qh[n][((3 * 4 + quad) ^ x) * 8];
        qb0 = *(const half8*)&qh[16 + n][((0 * 4 + quad) ^ x) * 8];
        qb1 = *(const half8*)&qh[16 + n][((1 * 4 + quad) ^ x) * 8];
        qb2 = *(const half8*)&qh[16 + n][((2 * 4 + quad) ^ x) * 8];
        qb3 = *(const half8*)&qh[16 + n][((3 * 4 + quad) ^ x) * 8];
    }

    // ---- P3: single pass, 16 chunks x 64 keys; 8 MFMA + branch-free top-2 ----
    float b1a = -3.4e38f, b2a = -3.4e38f; int i1a = 0;
    float b1b = -3.4e38f, b2b = -3.4e38f; int i1b = 0;
    // fragment-order: group g = ch*4+wid; fragment f at kh + (g*256 + f*64 + lane)*8
    const _Float16* kbase = kh + ((long)wid * 256 + lane) * 8;
    const int chOff = (int)(blockIdx.x >> 3) & 15;   // per-XCD sweep stagger

    for (int it = 0; it < 16; ++it) {
        int ch = (it + chOff) & 15;
        const _Float16* kp = kbase + (long)ch * 8192;   // 4 groups * 256 rows * 8
        half8 a0 = *(const half8*)(kp);
        half8 a1 = *(const half8*)(kp + 512);
        half8 a2 = *(const half8*)(kp + 1024);
        half8 a3 = *(const half8*)(kp + 1536);
        floatx4 accA = {0.f, 0.f, 0.f, 0.f};
        floatx4 accB = {0.f, 0.f, 0.f, 0.f};
        accA = MFMA16(a0, qa0, accA, 0, 0, 0);
        accA = MFMA16(a1, qa1, accA, 0, 0, 0);
        accA = MFMA16(a2, qa2, accA, 0, 0, 0);
        accA = MFMA16(a3, qa3, accA, 0, 0, 0);
        accB = MFMA16(a0, qb0, accB, 0, 0, 0);
        accB = MFMA16(a1, qb1, accB, 0, 0, 0);
        accB = MFMA16(a2, qb2, accB, 0, 0, 0);
        accB = MFMA16(a3, qb3, accB, 0, 0, 0);
        int keyb = ch * 64 + wid * 16 + quad * 4;

        // --- row block A (q rows 0..15): exact top-2 merge, branch-free ---
        {
            float s0 = accA[0], s1 = accA[1], s2 = accA[2], s3 = accA[3];
            float m01 = fmaxf(s0, s1), m23 = fmaxf(s2, s3);
            int   j01 = (s1 > s0) ? 1 : 0, j23 = (s3 > s2) ? 3 : 2;
            float c1 = fmaxf(m01, m23);
            int   jc = (m23 > m01) ? j23 : j01;
            float c2 = fmaxf(fminf(m01, m23), fmaxf(fminf(s0, s1), fminf(s2, s3)));
            bool better = c1 > b1a;
            b2a = fmaxf(fminf(b1a, c1), fmaxf(b2a, c2));
            b1a = fmaxf(b1a, c1);
            i1a = better ? (keyb + jc) : i1a;
        }
        // --- row block B (q rows 16..31) ---
        {
            float s0 = accB[0], s1 = accB[1], s2 = accB[2], s3 = accB[3];
            float m01 = fmaxf(s0, s1), m23 = fmaxf(s2, s3);
            int   j01 = (s1 > s0) ? 1 : 0, j23 = (s3 > s2) ? 3 : 2;
            float c1 = fmaxf(m01, m23);
            int   jc = (m23 > m01) ? j23 : j01;
            float c2 = fmaxf(fminf(m01, m23), fmaxf(fminf(s0, s1), fminf(s2, s3)));
            bool better = c1 > b1b;
            b2b = fmaxf(fminf(b1b, c1), fmaxf(b2b, c2));
            b1b = fmaxf(b1b, c1);
            i1b = better ? (keyb + jc) : i1b;
        }
    }

    // ---- P4: merge top-1 across quads (same q-row, disjoint keys) for M1 ----
    float mA = b1a; int jA = i1a; float mB = b1b; int jB = i1b;
    {
        float om; int oi;
        om = __shfl_xor(mA, 16); oi = __shfl_xor(jA, 16);
        if (om > mA || (om == mA && oi < jA)) { mA = om; jA = oi; }
        om = __shfl_xor(mA, 32); oi = __shfl_xor(jA, 32);
        if (om > mA || (om == mA && oi < jA)) { mA = om; jA = oi; }
        om = __shfl_xor(mB, 16); oi = __shfl_xor(jB, 16);
        if (om > mB || (om == mB && oi < jB)) { mB = om; jB = oi; }
        om = __shfl_xor(mB, 32); oi = __shfl_xor(jB, 32);
        if (om > mB || (om == mB && oi < jB)) { mB = om; jB = oi; }
    }
    if (lane < 16) {
        wm1[wid][n]      = mA; wi1[wid][n]      = jA;
        wm1[wid][16 + n] = mB; wi1[wid][16 + n] = jB;
    }
    __syncthreads();

    // ---- P5: merge across waves; rigorous candidate threshold ----
    if (t < T_ROWS) {
        float M1 = wm1[0][t]; int I1 = wi1[0][t];
        for (int w = 1; w < 4; ++w) {
            float om = wm1[w][t]; int oi = wi1[w][t];
            if (om > M1 || (om == M1 && oi < I1)) { M1 = om; I1 = oi; }
        }
        float qn2 = 0.f;
        for (int j = 0; j < 16; ++j) qn2 += qss[t][j];
        float qn = sqrtf(qn2);
        // fp16 rounding: |s~ - s| <= 2^-10*1.01*||q||*||k||max(<=17) + fp32-acc slack
        float e1 = 0.0168f * qn + 0.002f;
        // candidates compared are bit-identical register-held s~ values
        rowT[t]   = M1 - 2.f * e1 - 0.02f;
        rowI1s[t] = I1;
    }
    __syncthreads();

    // ---- P6: per-thread candidate push from register top-2 (no key reloads) ----
    {
        float thrA = rowT[n], thrB = rowT[16 + n];
        if (b1a >= thrA) {
            int pos = atomicAdd(&candCnt[n], 1);
            if (pos < 8) candKey[n][pos] = i1a; else rowOvf[n] = 1;
        }
        if (b2a >= thrA) rowOvf[n] = 1;   // 3rd-best unknown -> exact rescan
        if (b1b >= thrB) {
            int pos = atomicAdd(&candCnt[16 + n], 1);
            if (pos < 8) candKey[16 + n][pos] = i1b; else rowOvf[16 + n] = 1;
        }
        if (b2b >= thrB) rowOvf[16 + n] = 1;
    }
    __syncthreads();

    // ---- P7: exact fp32 rescoring of candidates; atomicMax packed (score,1023-key) ----
    {
        int row = t >> 3, slot = t & 7;    // 32 rows x 8 candidate slots
        int cnt = candCnt[row];
        if (!rowOvf[row] && slot < cnt) {
            int key = candKey[row][slot];
            const float* qp  = q + (g0 + row) * CDIM;
            const float* kp2 = keys + (long)key * CDIM;
            float acc0 = 0.f, acc1 = 0.f;
            for (int c = 0; c < CDIM; c += 8) {
                float4 qa = *(const float4*)(qp + c);
                float4 ka = *(const float4*)(kp2 + c);
                float4 qb = *(const float4*)(qp + c + 4);
                float4 kb4 = *(const float4*)(kp2 + c + 4);
                acc0 += qa.x*ka.x + qa.y*ka.y + qa.z*ka.z + qa.w*ka.w;
                acc1 += qb.x*kb4.x + qb.y*kb4.y + qb.z*kb4.z + qb.w*kb4.w;
            }
            FU su; su.f = acc0 + acc1;
            unsigned ord = (su.u & 0x80000000u) ? ~su.u : (su.u | 0x80000000u);
            unsigned long long enc = ((unsigned long long)ord << 32) | (unsigned)(1023 - key);
            atomicMax(&rowBest[row], enc);
        }
        // overflow fallback: exact rescan of all 1024 keys (rigor path, rare)
        for (int rr = 0; rr < T_ROWS; ++rr) {
            if (rowOvf[rr]) {
                const float* qp = q + (g0 + rr) * CDIM;
                #pragma unroll
                for (int kkk = 0; kkk < 4; ++kkk) {
                    int key = t * 4 + kkk;
                    const float* kp2 = keys + (long)key * CDIM;
                    float acc0 = 0.f, acc1 = 0.f;
                    for (int c = 0; c < CDIM; c += 8) {
                        float4 qa = *(const float4*)(qp + c);
                        float4 ka = *(const float4*)(kp2 + c);
                        float4 qb = *(const float4*)(qp + c + 4);
                        float4 kb4 = *(const float4*)(kp2 + c + 4);
                        acc0 += qa.x*ka.x + qa.y*ka.y + qa.z*ka.z + qa.w*ka.w;
                        acc1 += qb.x*kb4.x + qb.y*kb4.y + qb.z*kb4.z + qb.w*kb4.w;
                    }
                    FU su; su.f = acc0 + acc1;
                    unsigned ord = (su.u & 0x80000000u) ? ~su.u : (su.u | 0x80000000u);
                    unsigned long long enc = ((unsigned long long)ord << 32) | (unsigned)(1023 - key);
                    atomicMax(&rowBest[rr], enc);
                }
            }
        }
    }
    __syncthreads();

    // ---- P8: decode winning index ----
    if (t < T_ROWS) {
        unsigned long long b = rowBest[t];
        rowIdx[t] = b ? (1023 - (int)(unsigned)(b & 0xffffffffull)) : rowI1s[t];
    }
    __syncthreads();

    // ---- P9: fused gather: sum (q-k)^2 and (r-v)^2 in fp32 ----
    {
        int row0 = t >> 4, c8 = t & 15;
        #pragma unroll
        for (int h = 0; h < 2; ++h) {
            int rr = row0 + h * 16;
            int idx = rowIdx[rr];
            long g = g0 + rr;
            const float4* qp  = (const float4*)(q    + g * CDIM + c8 * 8);
            const float4* kp2 = (const float4*)(keys + (long)idx * CDIM + c8 * 8);
            const float4* rp  = (const float4*)(rep  + g * CDIM + c8 * 8);
            const float4* vp  = (const float4*)(vals + (long)idx * CDIM + c8 * 8);
            float kg = 0.f, vg = 0.f;
            #pragma unroll
            for (int hh = 0; hh < 2; ++hh) {
                float4 qa = qp[hh], ka = kp2[hh], ra = rp[hh], va = vp[hh];
                float d0 = qa.x - ka.x, d1 = qa.y - ka.y, d2 = qa.z - ka.z, d3 = qa.w - ka.w;
                kg += d0*d0 + d1*d1 + d2*d2 + d3*d3;
                float e0 = ra.x - va.x, e1 = ra.y - va.y, e2 = ra.z - va.z, e3 = ra.w - va.w;
                vg += e0*e0 + e1*e1 + e2*e2 + e3*e3;
            }
            kgp[rr][c8] = kg; vgp[rr][c8] = vg;
        }
    }
    __syncthreads();
    if (t < T_ROWS) {
        float a = 0.f, b = 0.f;
        for (int j = 0; j < 16; ++j) { a += kgp[t][j]; b += vgp[t][j]; }
        long g = g0 + t;
        out[g] = a;
        out[NROWS + g] = b;
    }
}

extern "C" void kernel_launch(void* const* d_in, const int* in_sizes, int n_in,
                              void* d_out, int out_size, void* d_ws, size_t ws_size,
                              hipStream_t stream) {
    const float* q    = (const float*)d_in[0];  // trend_representation
    const float* rep  = (const float*)d_in[1];  // representation
    const float* keys = (const float*)d_in[2];
    const float* vals = (const float*)d_in[3];
    _Float16* kh = (_Float16*)d_ws;             // 256 KB fp16 key cache (fragment order)

    cvt_keys_kernel<<<128, 256, 0, stream>>>(keys, kh);
    gather_main<<<NROWS / T_ROWS, 256, 0, stream>>>(q, rep, keys, vals, kh,
                                                    (float*)d_out);
}

// Round 5
// 258.199 us; speedup vs baseline: 1.0039x; 1.0039x over previous
//
#include <hip/hip_runtime.h>

#define T_ROWS 32
#define NROWS  65536
#define CDIM   128
#define MKEYS  1024

typedef _Float16 half8 __attribute__((ext_vector_type(8)));
typedef _Float16 half4 __attribute__((ext_vector_type(4)));
typedef float    floatx4 __attribute__((ext_vector_type(4)));

union FU { float f; unsigned u; };

#define MFMA16 __builtin_amdgcn_mfma_f32_16x16x32_f16

// fire-and-forget global->LDS DMA, 16B per lane: LDS dst = uniform base + lane*16
__device__ __forceinline__ void gl_lds16(const _Float16* g, _Float16* l) {
    __builtin_amdgcn_global_load_lds(
        (__attribute__((address_space(1))) unsigned int*)g,
        (__attribute__((address_space(3))) unsigned int*)l,
        16, 0, 0);
}

// ---------------- Kernel A: convert keys fp32 -> fp16 in MFMA-fragment order --------
// Layout: for key k, dim d:  g=k>>4, n=k&15, f=d>>5, q8=(d&31)>>3, e=d&7
//   kh[ ((g*4+f)*64 + q8*16 + n)*8 + e ]  = (fp16) keys[k][d]
// With lane = q8*16+n, fragment-f load for key group g is
// kh + (g*256 + f*64 + lane)*8 : 64 lanes x 16B fully contiguous (1KB/instr) --
// exactly the per-lane source pattern global_load_lds requires.
__global__ __launch_bounds__(256) void cvt_keys_kernel(const float* __restrict__ keys,
                                                       _Float16* __restrict__ kh) {
    int i  = blockIdx.x * 256 + threadIdx.x;        // 32768 threads
    int k  = i >> 5;                                // key 0..1023
    int d0 = (i & 31) * 4;                          // dim 0,4,...,124
    float4 f4 = *(const float4*)(keys + (long)k * CDIM + d0);
    half4 hv;
    hv[0] = (_Float16)f4.x; hv[1] = (_Float16)f4.y;
    hv[2] = (_Float16)f4.z; hv[3] = (_Float16)f4.w;
    int g = k >> 4, n = k & 15;
    int f = d0 >> 5, q8 = (d0 & 31) >> 3, e = d0 & 7;
    long idx = ((long)((g * 4 + f) * 64 + q8 * 16 + n)) * 8 + e;
    *(half4*)(kh + idx) = hv;
}

// ---------------- Kernel B: fused score/argmax/rescue/gather, 32 rows/block ----------
// K-loop v5: double-buffered LDS staging via global_load_lds, ZERO barriers in the
// hot loop. Each wave stages and consumes only its own wid-quarter of each 64-key
// chunk, so no cross-wave visibility is needed; ordering is per-wave counted
// s_waitcnt vmcnt(4) (next batch stays in flight). Loads never block the wave on
// L2 latency; MFMA operands come from LDS (ds_read_b128, 2-way-free pattern).
// Top-2 / threshold / rescue logic identical to R3/R4 (correctness-proven).
__global__ __launch_bounds__(256, 4) void gather_main(
    const float* __restrict__ q,      // trend_representation (65536x128)
    const float* __restrict__ rep,    // representation
    const float* __restrict__ keys,   // fp32 keys (1024x128)
    const float* __restrict__ vals,   // fp32 values
    const _Float16* __restrict__ kh,  // fp16 keys, fragment order (ws)
    float* __restrict__ out)          // [131072]: keys_g then values_g
{
    // Phase-disjoint LDS overlay: qh (P1/P2) -> kbuf (P3) -> kgp/vgp (P9).
    // Barriers separate all three uses.
    __shared__ union {
        _Float16 qh[T_ROWS][128];                 // 8 KB
        _Float16 kbuf[2][8192];                   // 2 x 16 KB double buffer
        struct { float kgp[T_ROWS][17]; float vgp[T_ROWS][17]; } g;
    } u;
    __shared__ float qss[T_ROWS][17];             // per-(row,c8) sumsq, padded
    __shared__ float wm1[4][T_ROWS];
    __shared__ int   wi1[4][T_ROWS];
    __shared__ float rowT[T_ROWS];
    __shared__ int   rowI1s[T_ROWS];
    __shared__ int   candCnt[T_ROWS];
    __shared__ int   candKey[T_ROWS][8];
    __shared__ int   rowOvf[T_ROWS];
    __shared__ unsigned long long rowBest[T_ROWS];
    __shared__ int   rowIdx[T_ROWS];

    const int t    = threadIdx.x;
    const int wid  = t >> 6;
    const int lane = t & 63;
    const int n    = lane & 15;       // A: key-in-16, B/C: q-row (col) in 16
    const int quad = lane >> 4;       // k-chunk selector / C row group
    const long g0  = (long)blockIdx.x * T_ROWS;

    if (t < T_ROWS) { candCnt[t] = 0; rowOvf[t] = 0; rowBest[t] = 0ull; }

    // ---- P1: stage q tile -> fp16 LDS (swizzled), per-(row,chunk) sumsq ----
    {
        int row = t >> 4, c8 = t & 15;
        #pragma unroll
        for (int h = 0; h < 2; ++h) {
            int rr = row + h * 16;
            const float4* src = (const float4*)(q + (g0 + rr) * CDIM + c8 * 8);
            float4 a0 = src[0], a1 = src[1];
            qss[rr][c8] = a0.x*a0.x + a0.y*a0.y + a0.z*a0.z + a0.w*a0.w
                        + a1.x*a1.x + a1.y*a1.y + a1.z*a1.z + a1.w*a1.w;
            half8 hv;
            hv[0] = (_Float16)a0.x; hv[1] = (_Float16)a0.y;
            hv[2] = (_Float16)a0.z; hv[3] = (_Float16)a0.w;
            hv[4] = (_Float16)a1.x; hv[5] = (_Float16)a1.y;
            hv[6] = (_Float16)a1.z; hv[7] = (_Float16)a1.w;
            int phys = c8 ^ (rr & 7);
            *(half8*)&u.qh[rr][phys * 8] = hv;
        }
    }
    __syncthreads();

    // ---- P2: hoist B-fragments (q rows n and 16+n) into registers ----
    half8 qa0, qa1, qa2, qa3, qb0, qb1, qb2, qb3;
    {
        int x = n & 7;
        qa0 = *(const half8*)&u.qh[n][((0 * 4 + quad) ^ x) * 8];
        qa1 = *(const half8*)&u.qh[n][((1 * 4 + quad) ^ x) * 8];
        qa2 = *(const half8*)&u.qh[n][((2 * 4 + quad) ^ x) * 8];
        qa3 = *(const half8*)&u.qh[n][((3 * 4 + quad) ^ x) * 8];
        qb0 = *(const half8*)&u.qh[16 + n][((0 * 4 + quad) ^ x) * 8];
        qb1 = *(const half8*)&u.qh[16 + n][((1 * 4 + quad) ^ x) * 8];
        qb2 = *(const half8*)&u.qh[16 + n][((2 * 4 + quad) ^ x) * 8];
        qb3 = *(const half8*)&u.qh[16 + n][((3 * 4 + quad) ^ x) * 8];
    }
    __syncthreads();   // all waves done reading qh before kbuf staging overwrites it

    // ---- P3: 16 chunks x 64 keys; LDS double-buffer, barrier-free ----
    float b1a = -3.4e38f, b2a = -3.4e38f; int i1a = 0;
    float b1b = -3.4e38f, b2b = -3.4e38f; int i1b = 0;

    _Float16* kb0 = &u.kbuf[0][wid * 2048];                 // my 4KB quarter, buf 0
    _Float16* kb1 = &u.kbuf[1][wid * 2048];                 // my 4KB quarter, buf 1
    const _Float16* gk = kh + ((long)wid * 256 + lane) * 8; // per-lane global src

#define STAGE(ch, ldst) {                                   \
        const _Float16* gs_ = gk + (long)(ch) * 8192;       \
        gl_lds16(gs_,        (ldst));                       \
        gl_lds16(gs_ +  512, (ldst) +  512);                \
        gl_lds16(gs_ + 1024, (ldst) + 1024);                \
        gl_lds16(gs_ + 1536, (ldst) + 1536); }

#define CONSUME(bptr, ch) {                                              \
        const _Float16* kp_ = (bptr) + lane * 8;                         \
        half8 a0 = *(const half8*)(kp_);                                 \
        half8 a1 = *(const half8*)(kp_ + 512);                           \
        half8 a2 = *(const half8*)(kp_ + 1024);                          \
        half8 a3 = *(const half8*)(kp_ + 1536);                          \
        floatx4 accA = {0.f, 0.f, 0.f, 0.f};                             \
        floatx4 accB = {0.f, 0.f, 0.f, 0.f};                             \
        accA = MFMA16(a0, qa0, accA, 0, 0, 0);                           \
        accA = MFMA16(a1, qa1, accA, 0, 0, 0);                           \
        accA = MFMA16(a2, qa2, accA, 0, 0, 0);                           \
        accA = MFMA16(a3, qa3, accA, 0, 0, 0);                           \
        accB = MFMA16(a0, qb0, accB, 0, 0, 0);                           \
        accB = MFMA16(a1, qb1, accB, 0, 0, 0);                           \
        accB = MFMA16(a2, qb2, accB, 0, 0, 0);                           \
        accB = MFMA16(a3, qb3, accB, 0, 0, 0);                           \
        int keyb_ = (ch) * 64 + wid * 16 + quad * 4;                     \
        {                                                                \
            float s0 = accA[0], s1 = accA[1], s2 = accA[2], s3 = accA[3];\
            float m01 = fmaxf(s0, s1), m23 = fmaxf(s2, s3);              \
            int   j01 = (s1 > s0) ? 1 : 0, j23 = (s3 > s2) ? 3 : 2;      \
            float c1 = fmaxf(m01, m23);                                  \
            int   jc = (m23 > m01) ? j23 : j01;                          \
            float c2 = fmaxf(fminf(m01, m23),                            \
                             fmaxf(fminf(s0, s1), fminf(s2, s3)));       \
            bool better = c1 > b1a;                                      \
            b2a = fmaxf(fminf(b1a, c1), fmaxf(b2a, c2));                 \
            b1a = fmaxf(b1a, c1);                                        \
            i1a = better ? (keyb_ + jc) : i1a;                           \
        }                                                                \
        {                                                                \
            float s0 = accB[0], s1 = accB[1], s2 = accB[2], s3 = accB[3];\
            float m01 = fmaxf(s0, s1), m23 = fmaxf(s2, s3);              \
            int   j01 = (s1 > s0) ? 1 : 0, j23 = (s3 > s2) ? 3 : 2;      \
            float c1 = fmaxf(m01, m23);                                  \
            int   jc = (m23 > m01) ? j23 : j01;                          \
            float c2 = fmaxf(fminf(m01, m23),                            \
                             fmaxf(fminf(s0, s1), fminf(s2, s3)));       \
            bool better = c1 > b1b;                                      \
            b2b = fmaxf(fminf(b1b, c1), fmaxf(b2b, c2));                 \
            b1b = fmaxf(b1b, c1);                                        \
            i1b = better ? (keyb_ + jc) : i1b;                           \
        }                                                                \
    }

    STAGE(0, kb0);
    for (int it = 0; it < 15; ++it) {
        _Float16* nb = (it & 1) ? kb0 : kb1;     // buffer for batch it+1
        STAGE(it + 1, nb);
        // wait batch it (4 oldest DMAs) done; batch it+1 (4) stays in flight
        asm volatile("s_waitcnt vmcnt(4)" ::: "memory");
        __builtin_amdgcn_sched_barrier(0);
        const _Float16* cb = (it & 1) ? kb1 : kb0;
        CONSUME(cb, it);
    }
    asm volatile("s_waitcnt vmcnt(0)" ::: "memory");
    __builtin_amdgcn_sched_barrier(0);
    CONSUME(kb1, 15);

    // ---- P4: merge top-1 across quads (same q-row, disjoint keys) for M1 ----
    float mA = b1a; int jA = i1a; float mB = b1b; int jB = i1b;
    {
        float om; int oi;
        om = __shfl_xor(mA, 16); oi = __shfl_xor(jA, 16);
        if (om > mA || (om == mA && oi < jA)) { mA = om; jA = oi; }
        om = __shfl_xor(mA, 32); oi = __shfl_xor(jA, 32);
        if (om > mA || (om == mA && oi < jA)) { mA = om; jA = oi; }
        om = __shfl_xor(mB, 16); oi = __shfl_xor(jB, 16);
        if (om > mB || (om == mB && oi < jB)) { mB = om; jB = oi; }
        om = __shfl_xor(mB, 32); oi = __shfl_xor(jB, 32);
        if (om > mB || (om == mB && oi < jB)) { mB = om; jB = oi; }
    }
    if (lane < 16) {
        wm1[wid][n]      = mA; wi1[wid][n]      = jA;
        wm1[wid][16 + n] = mB; wi1[wid][16 + n] = jB;
    }
    __syncthreads();

    // ---- P5: merge across waves; rigorous candidate threshold ----
    if (t < T_ROWS) {
        float M1 = wm1[0][t]; int I1 = wi1[0][t];
        for (int w = 1; w < 4; ++w) {
            float om = wm1[w][t]; int oi = wi1[w][t];
            if (om > M1 || (om == M1 && oi < I1)) { M1 = om; I1 = oi; }
        }
        float qn2 = 0.f;
        for (int j = 0; j < 16; ++j) qn2 += qss[t][j];
        float qn = sqrtf(qn2);
        // fp16 rounding: |s~ - s| <= 2^-10*1.01*||q||*||k||max(<=17) + fp32-acc slack
        float e1 = 0.0168f * qn + 0.002f;
        // candidates compared are bit-identical register-held s~ values
        rowT[t]   = M1 - 2.f * e1 - 0.02f;
        rowI1s[t] = I1;
    }
    __syncthreads();

    // ---- P6: per-thread candidate push from register top-2 (no key reloads) ----
    {
        float thrA = rowT[n], thrB = rowT[16 + n];
        if (b1a >= thrA) {
            int pos = atomicAdd(&candCnt[n], 1);
            if (pos < 8) candKey[n][pos] = i1a; else rowOvf[n] = 1;
        }
        if (b2a >= thrA) rowOvf[n] = 1;   // 3rd-best unknown -> exact rescan
        if (b1b >= thrB) {
            int pos = atomicAdd(&candCnt[16 + n], 1);
            if (pos < 8) candKey[16 + n][pos] = i1b; else rowOvf[16 + n] = 1;
        }
        if (b2b >= thrB) rowOvf[16 + n] = 1;
    }
    __syncthreads();

    // ---- P7: exact fp32 rescoring of candidates; atomicMax packed (score,1023-key) ----
    {
        int row = t >> 3, slot = t & 7;    // 32 rows x 8 candidate slots
        int cnt = candCnt[row];
        if (!rowOvf[row] && slot < cnt) {
            int key = candKey[row][slot];
            const float* qp  = q + (g0 + row) * CDIM;
            const float* kp2 = keys + (long)key * CDIM;
            float acc0 = 0.f, acc1 = 0.f;
            for (int c = 0; c < CDIM; c += 8) {
                float4 qa = *(const float4*)(qp + c);
                float4 ka = *(const float4*)(kp2 + c);
                float4 qb = *(const float4*)(qp + c + 4);
                float4 kb4 = *(const float4*)(kp2 + c + 4);
                acc0 += qa.x*ka.x + qa.y*ka.y + qa.z*ka.z + qa.w*ka.w;
                acc1 += qb.x*kb4.x + qb.y*kb4.y + qb.z*kb4.z + qb.w*kb4.w;
            }
            FU su; su.f = acc0 + acc1;
            unsigned ord = (su.u & 0x80000000u) ? ~su.u : (su.u | 0x80000000u);
            unsigned long long enc = ((unsigned long long)ord << 32) | (unsigned)(1023 - key);
            atomicMax(&rowBest[row], enc);
        }
        // overflow fallback: exact rescan of all 1024 keys (rigor path, rare)
        for (int rr = 0; rr < T_ROWS; ++rr) {
            if (rowOvf[rr]) {
                const float* qp = q + (g0 + rr) * CDIM;
                #pragma unroll
                for (int kkk = 0; kkk < 4; ++kkk) {
                    int key = t * 4 + kkk;
                    const float* kp2 = keys + (long)key * CDIM;
                    float acc0 = 0.f, acc1 = 0.f;
                    for (int c = 0; c < CDIM; c += 8) {
                        float4 qa = *(const float4*)(qp + c);
                        float4 ka = *(const float4*)(kp2 + c);
                        float4 qb = *(const float4*)(qp + c + 4);
                        float4 kb4 = *(const float4*)(kp2 + c + 4);
                        acc0 += qa.x*ka.x + qa.y*ka.y + qa.z*ka.z + qa.w*ka.w;
                        acc1 += qb.x*kb4.x + qb.y*kb4.y + qb.z*kb4.z + qb.w*kb4.w;
                    }
                    FU su; su.f = acc0 + acc1;
                    unsigned ord = (su.u & 0x80000000u) ? ~su.u : (su.u | 0x80000000u);
                    unsigned long long enc = ((unsigned long long)ord << 32) | (unsigned)(1023 - key);
                    atomicMax(&rowBest[rr], enc);
                }
            }
        }
    }
    __syncthreads();

    // ---- P8: decode winning index ----
    if (t < T_ROWS) {
        unsigned long long b = rowBest[t];
        rowIdx[t] = b ? (1023 - (int)(unsigned)(b & 0xffffffffull)) : rowI1s[t];
    }
    __syncthreads();

    // ---- P9: fused gather: sum (q-k)^2 and (r-v)^2 in fp32 ----
    {
        int row0 = t >> 4, c8 = t & 15;
        #pragma unroll
        for (int h = 0; h < 2; ++h) {
            int rr = row0 + h * 16;
            int idx = rowIdx[rr];
            long g = g0 + rr;
            const float4* qp  = (const float4*)(q    + g * CDIM + c8 * 8);
            const float4* kp2 = (const float4*)(keys + (long)idx * CDIM + c8 * 8);
            const float4* rp  = (const float4*)(rep  + g * CDIM + c8 * 8);
            const float4* vp  = (const float4*)(vals + (long)idx * CDIM + c8 * 8);
            float kg = 0.f, vg = 0.f;
            #pragma unroll
            for (int hh = 0; hh < 2; ++hh) {
                float4 qa = qp[hh], ka = kp2[hh], ra = rp[hh], va = vp[hh];
                float d0 = qa.x - ka.x, d1 = qa.y - ka.y, d2 = qa.z - ka.z, d3 = qa.w - ka.w;
                kg += d0*d0 + d1*d1 + d2*d2 + d3*d3;
                float e0 = ra.x - va.x, e1 = ra.y - va.y, e2 = ra.z - va.z, e3 = ra.w - va.w;
                vg += e0*e0 + e1*e1 + e2*e2 + e3*e3;
            }
            u.g.kgp[rr][c8] = kg; u.g.vgp[rr][c8] = vg;
        }
    }
    __syncthreads();
    if (t < T_ROWS) {
        float a = 0.f, b = 0.f;
        for (int j = 0; j < 16; ++j) { a += u.g.kgp[t][j]; b += u.g.vgp[t][j]; }
        long g = g0 + t;
        out[g] = a;
        out[NROWS + g] = b;
    }
}

extern "C" void kernel_launch(void* const* d_in, const int* in_sizes, int n_in,
                              void* d_out, int out_size, void* d_ws, size_t ws_size,
                              hipStream_t stream) {
    const float* q    = (const float*)d_in[0];  // trend_representation
    const float* rep  = (const float*)d_in[1];  // representation
    const float* keys = (const float*)d_in[2];
    const float* vals = (const float*)d_in[3];
    _Float16* kh = (_Float16*)d_ws;             // 256 KB fp16 key cache (fragment order)

    cvt_keys_kernel<<<128, 256, 0, stream>>>(keys, kh);
    gather_main<<<NROWS / T_ROWS, 256, 0, stream>>>(q, rep, keys, vals, kh,
                                                    (float*)d_out);
}

// Round 6
// 237.119 us; speedup vs baseline: 1.0932x; 1.0889x over previous
//
#include <hip/hip_runtime.h>

#define T_ROWS 64
#define NROWS  65536
#define CDIM   128
#define MKEYS  1024

typedef _Float16 half8 __attribute__((ext_vector_type(8)));
typedef _Float16 half4 __attribute__((ext_vector_type(4)));
typedef float    floatx4 __attribute__((ext_vector_type(4)));

union FU { float f; unsigned u; };

#define MFMA16 __builtin_amdgcn_mfma_f32_16x16x32_f16

// ---------------- Kernel A: convert keys fp32 -> fp16 in MFMA-fragment order --------
// Layout: for key k, dim d:  g=k>>4, n=k&15, f=d>>5, q8=(d&31)>>3, e=d&7
//   kh[ ((g*4+f)*64 + q8*16 + n)*8 + e ]  = (fp16) keys[k][d]
// With lane = q8*16+n, fragment-f load for key group g is
// kh + (g*256 + f*64 + lane)*8 : 64 lanes x 16B fully contiguous (1KB/instr).
__global__ __launch_bounds__(256) void cvt_keys_kernel(const float* __restrict__ keys,
                                                       _Float16* __restrict__ kh) {
    int i  = blockIdx.x * 256 + threadIdx.x;        // 32768 threads
    int k  = i >> 5;                                // key 0..1023
    int d0 = (i & 31) * 4;                          // dim 0,4,...,124
    float4 f4 = *(const float4*)(keys + (long)k * CDIM + d0);
    half4 hv;
    hv[0] = (_Float16)f4.x; hv[1] = (_Float16)f4.y;
    hv[2] = (_Float16)f4.z; hv[3] = (_Float16)f4.w;
    int g = k >> 4, n = k & 15;
    int f = d0 >> 5, q8 = (d0 & 31) >> 3, e = d0 & 7;
    long idx = ((long)((g * 4 + f) * 64 + q8 * 16 + n)) * 8 + e;
    *(half4*)(kh + idx) = hv;
}

// ---------------- Kernel B: fused score/argmax/rescue/gather, 64 rows/block ----------
// T_ROWS=64: halves total shared-key traffic (1024 blocks x 256KB) and doubles
// independent MFMA/VALU work per wave (4 acc chains). K-loop = R3's proven
// coalesced register-load form. Top-2 / threshold / rescue logic per row set,
// identical math to the correctness-proven 32-row version.
__global__ __launch_bounds__(256, 4) void gather_main(
    const float* __restrict__ q,      // trend_representation (65536x128)
    const float* __restrict__ rep,    // representation
    const float* __restrict__ keys,   // fp32 keys (1024x128)
    const float* __restrict__ vals,   // fp32 values
    const _Float16* __restrict__ kh,  // fp16 keys, fragment order (ws)
    float* __restrict__ out)          // [131072]: keys_g then values_g
{
    __shared__ _Float16 qh[T_ROWS][128];          // fp16 q, swizzled (16 KB)
    __shared__ float qss[T_ROWS][17];             // per-(row,c8) sumsq, padded
    __shared__ float wm1[4][T_ROWS];
    __shared__ int   wi1[4][T_ROWS];
    __shared__ float rowT[T_ROWS];
    __shared__ int   rowI1s[T_ROWS];
    __shared__ int   candCnt[T_ROWS];
    __shared__ int   candKey[T_ROWS][4];
    __shared__ int   rowOvf[T_ROWS];
    __shared__ unsigned long long rowBest[T_ROWS];
    __shared__ int   rowIdx[T_ROWS];
    __shared__ float kgp[T_ROWS][17], vgp[T_ROWS][17];

    const int t    = threadIdx.x;
    const int wid  = t >> 6;
    const int lane = t & 63;
    const int n    = lane & 15;       // A: key-in-16, B/C: q-row (col) in 16
    const int quad = lane >> 4;       // k-chunk selector / C row group
    const long g0  = (long)blockIdx.x * T_ROWS;

    if (t < T_ROWS) { candCnt[t] = 0; rowOvf[t] = 0; rowBest[t] = 0ull; }

    // ---- P1: stage q tile -> fp16 LDS (swizzled), per-(row,chunk) sumsq ----
    {
        int row = t >> 4, c8 = t & 15;
        #pragma unroll
        for (int h = 0; h < 4; ++h) {
            int rr = row + h * 16;
            const float4* src = (const float4*)(q + (g0 + rr) * CDIM + c8 * 8);
            float4 a0 = src[0], a1 = src[1];
            qss[rr][c8] = a0.x*a0.x + a0.y*a0.y + a0.z*a0.z + a0.w*a0.w
                        + a1.x*a1.x + a1.y*a1.y + a1.z*a1.z + a1.w*a1.w;
            half8 hv;
            hv[0] = (_Float16)a0.x; hv[1] = (_Float16)a0.y;
            hv[2] = (_Float16)a0.z; hv[3] = (_Float16)a0.w;
            hv[4] = (_Float16)a1.x; hv[5] = (_Float16)a1.y;
            hv[6] = (_Float16)a1.z; hv[7] = (_Float16)a1.w;
            int phys = c8 ^ (rr & 7);
            *(half8*)&qh[rr][phys * 8] = hv;
        }
    }
    __syncthreads();

    // ---- P2: hoist B-fragments (q rows n, 16+n, 32+n, 48+n) into registers ----
    half8 qa0, qa1, qa2, qa3, qb0, qb1, qb2, qb3;
    half8 qc0, qc1, qc2, qc3, qd0, qd1, qd2, qd3;
    {
        int x = n & 7;
        int p0 = ((0 * 4 + quad) ^ x) * 8;
        int p1 = ((1 * 4 + quad) ^ x) * 8;
        int p2 = ((2 * 4 + quad) ^ x) * 8;
        int p3 = ((3 * 4 + quad) ^ x) * 8;
        qa0 = *(const half8*)&qh[n][p0];      qa1 = *(const half8*)&qh[n][p1];
        qa2 = *(const half8*)&qh[n][p2];      qa3 = *(const half8*)&qh[n][p3];
        qb0 = *(const half8*)&qh[16 + n][p0]; qb1 = *(const half8*)&qh[16 + n][p1];
        qb2 = *(const half8*)&qh[16 + n][p2]; qb3 = *(const half8*)&qh[16 + n][p3];
        qc0 = *(const half8*)&qh[32 + n][p0]; qc1 = *(const half8*)&qh[32 + n][p1];
        qc2 = *(const half8*)&qh[32 + n][p2]; qc3 = *(const half8*)&qh[32 + n][p3];
        qd0 = *(const half8*)&qh[48 + n][p0]; qd1 = *(const half8*)&qh[48 + n][p1];
        qd2 = *(const half8*)&qh[48 + n][p2]; qd3 = *(const half8*)&qh[48 + n][p3];
    }

    // ---- P3: 16 chunks x 64 keys; 16 MFMA (4 indep chains) + branch-free top-2 ----
    float b1a = -3.4e38f, b2a = -3.4e38f; int i1a = 0;
    float b1b = -3.4e38f, b2b = -3.4e38f; int i1b = 0;
    float b1c = -3.4e38f, b2c = -3.4e38f; int i1c = 0;
    float b1d = -3.4e38f, b2d = -3.4e38f; int i1d = 0;
    // fragment-order: group g = ch*4+wid; fragment f at kh + (g*256 + f*64 + lane)*8
    const _Float16* kbase = kh + ((long)wid * 256 + lane) * 8;

#define TOP2(s_, b1_, b2_, i1_, keyb_) {                                      \
        float s0 = s_[0], s1 = s_[1], s2 = s_[2], s3 = s_[3];                 \
        float m01 = fmaxf(s0, s1), m23 = fmaxf(s2, s3);                       \
        int   j01 = (s1 > s0) ? 1 : 0, j23 = (s3 > s2) ? 3 : 2;               \
        float c1 = fmaxf(m01, m23);                                           \
        int   jc = (m23 > m01) ? j23 : j01;                                   \
        float c2 = fmaxf(fminf(m01, m23), fmaxf(fminf(s0, s1), fminf(s2, s3)));\
        bool better = c1 > b1_;                                               \
        b2_ = fmaxf(fminf(b1_, c1), fmaxf(b2_, c2));                          \
        b1_ = fmaxf(b1_, c1);                                                 \
        i1_ = better ? ((keyb_) + jc) : i1_; }

    for (int ch = 0; ch < 16; ++ch) {
        const _Float16* kp = kbase + (long)ch * 8192;   // 4 groups * 256 rows * 8
        half8 a0 = *(const half8*)(kp);
        half8 a1 = *(const half8*)(kp + 512);
        half8 a2 = *(const half8*)(kp + 1024);
        half8 a3 = *(const half8*)(kp + 1536);
        floatx4 accA = {0.f, 0.f, 0.f, 0.f};
        floatx4 accB = {0.f, 0.f, 0.f, 0.f};
        floatx4 accC = {0.f, 0.f, 0.f, 0.f};
        floatx4 accD = {0.f, 0.f, 0.f, 0.f};
        accA = MFMA16(a0, qa0, accA, 0, 0, 0);
        accB = MFMA16(a0, qb0, accB, 0, 0, 0);
        accC = MFMA16(a0, qc0, accC, 0, 0, 0);
        accD = MFMA16(a0, qd0, accD, 0, 0, 0);
        accA = MFMA16(a1, qa1, accA, 0, 0, 0);
        accB = MFMA16(a1, qb1, accB, 0, 0, 0);
        accC = MFMA16(a1, qc1, accC, 0, 0, 0);
        accD = MFMA16(a1, qd1, accD, 0, 0, 0);
        accA = MFMA16(a2, qa2, accA, 0, 0, 0);
        accB = MFMA16(a2, qb2, accB, 0, 0, 0);
        accC = MFMA16(a2, qc2, accC, 0, 0, 0);
        accD = MFMA16(a2, qd2, accD, 0, 0, 0);
        accA = MFMA16(a3, qa3, accA, 0, 0, 0);
        accB = MFMA16(a3, qb3, accB, 0, 0, 0);
        accC = MFMA16(a3, qc3, accC, 0, 0, 0);
        accD = MFMA16(a3, qd3, accD, 0, 0, 0);
        int keyb = ch * 64 + wid * 16 + quad * 4;
        TOP2(accA, b1a, b2a, i1a, keyb);
        TOP2(accB, b1b, b2b, i1b, keyb);
        TOP2(accC, b1c, b2c, i1c, keyb);
        TOP2(accD, b1d, b2d, i1d, keyb);
    }

    // ---- P4: merge top-1 across quads (same q-row, disjoint keys) for M1 ----
#define QMERGE(m_, j_) {                                                   \
        float om; int oi;                                                  \
        om = __shfl_xor(m_, 16); oi = __shfl_xor(j_, 16);                  \
        if (om > m_ || (om == m_ && oi < j_)) { m_ = om; j_ = oi; }        \
        om = __shfl_xor(m_, 32); oi = __shfl_xor(j_, 32);                  \
        if (om > m_ || (om == m_ && oi < j_)) { m_ = om; j_ = oi; } }

    float mA = b1a; int jA = i1a; float mB = b1b; int jB = i1b;
    float mC = b1c; int jC = i1c; float mD = b1d; int jD = i1d;
    QMERGE(mA, jA); QMERGE(mB, jB); QMERGE(mC, jC); QMERGE(mD, jD);
    if (lane < 16) {
        wm1[wid][n]      = mA; wi1[wid][n]      = jA;
        wm1[wid][16 + n] = mB; wi1[wid][16 + n] = jB;
        wm1[wid][32 + n] = mC; wi1[wid][32 + n] = jC;
        wm1[wid][48 + n] = mD; wi1[wid][48 + n] = jD;
    }
    __syncthreads();

    // ---- P5: merge across waves; rigorous candidate threshold ----
    if (t < T_ROWS) {
        float M1 = wm1[0][t]; int I1 = wi1[0][t];
        for (int w = 1; w < 4; ++w) {
            float om = wm1[w][t]; int oi = wi1[w][t];
            if (om > M1 || (om == M1 && oi < I1)) { M1 = om; I1 = oi; }
        }
        float qn2 = 0.f;
        for (int j = 0; j < 16; ++j) qn2 += qss[t][j];
        float qn = sqrtf(qn2);
        // fp16 rounding: |s~ - s| <= 2^-10*1.01*||q||*||k||max(<=17) + fp32-acc slack
        float e1 = 0.0168f * qn + 0.002f;
        // candidates compared are bit-identical register-held s~ values
        rowT[t]   = M1 - 2.f * e1 - 0.02f;
        rowI1s[t] = I1;
    }
    __syncthreads();

    // ---- P6: per-thread candidate push from register top-2 (no key reloads) ----
    {
#define PUSH(b1_, b2_, i1_, row_) {                                        \
        float thr_ = rowT[row_];                                           \
        if (b1_ >= thr_) {                                                 \
            int pos = atomicAdd(&candCnt[row_], 1);                        \
            if (pos < 4) candKey[row_][pos] = i1_; else rowOvf[row_] = 1;  \
        }                                                                  \
        if (b2_ >= thr_) rowOvf[row_] = 1; }
        PUSH(b1a, b2a, i1a, n);
        PUSH(b1b, b2b, i1b, 16 + n);
        PUSH(b1c, b2c, i1c, 32 + n);
        PUSH(b1d, b2d, i1d, 48 + n);
    }
    __syncthreads();

    // ---- P7: exact fp32 rescoring of candidates; atomicMax packed (score,1023-key) ----
    {
        int row = t >> 2, slot = t & 3;    // 64 rows x 4 candidate slots
        int cnt = candCnt[row];
        if (!rowOvf[row] && slot < cnt) {
            int key = candKey[row][slot];
            const float* qp  = q + (g0 + row) * CDIM;
            const float* kp2 = keys + (long)key * CDIM;
            float acc0 = 0.f, acc1 = 0.f;
            for (int c = 0; c < CDIM; c += 8) {
                float4 qa = *(const float4*)(qp + c);
                float4 ka = *(const float4*)(kp2 + c);
                float4 qb = *(const float4*)(qp + c + 4);
                float4 kb4 = *(const float4*)(kp2 + c + 4);
                acc0 += qa.x*ka.x + qa.y*ka.y + qa.z*ka.z + qa.w*ka.w;
                acc1 += qb.x*kb4.x + qb.y*kb4.y + qb.z*kb4.z + qb.w*kb4.w;
            }
            FU su; su.f = acc0 + acc1;
            unsigned ord = (su.u & 0x80000000u) ? ~su.u : (su.u | 0x80000000u);
            unsigned long long enc = ((unsigned long long)ord << 32) | (unsigned)(1023 - key);
            atomicMax(&rowBest[row], enc);
        }
        // overflow fallback: exact rescan of all 1024 keys (rigor path, rare)
        for (int rr = 0; rr < T_ROWS; ++rr) {
            if (rowOvf[rr]) {
                const float* qp = q + (g0 + rr) * CDIM;
                #pragma unroll
                for (int kkk = 0; kkk < 4; ++kkk) {
                    int key = t * 4 + kkk;
                    const float* kp2 = keys + (long)key * CDIM;
                    float acc0 = 0.f, acc1 = 0.f;
                    for (int c = 0; c < CDIM; c += 8) {
                        float4 qa = *(const float4*)(qp + c);
                        float4 ka = *(const float4*)(kp2 + c);
                        float4 qb = *(const float4*)(qp + c + 4);
                        float4 kb4 = *(const float4*)(kp2 + c + 4);
                        acc0 += qa.x*ka.x + qa.y*ka.y + qa.z*ka.z + qa.w*ka.w;
                        acc1 += qb.x*kb4.x + qb.y*kb4.y + qb.z*kb4.z + qb.w*kb4.w;
                    }
                    FU su; su.f = acc0 + acc1;
                    unsigned ord = (su.u & 0x80000000u) ? ~su.u : (su.u | 0x80000000u);
                    unsigned long long enc = ((unsigned long long)ord << 32) | (unsigned)(1023 - key);
                    atomicMax(&rowBest[rr], enc);
                }
            }
        }
    }
    __syncthreads();

    // ---- P8: decode winning index ----
    if (t < T_ROWS) {
        unsigned long long b = rowBest[t];
        rowIdx[t] = b ? (1023 - (int)(unsigned)(b & 0xffffffffull)) : rowI1s[t];
    }
    __syncthreads();

    // ---- P9: fused gather: sum (q-k)^2 and (r-v)^2 in fp32 ----
    {
        int row0 = t >> 4, c8 = t & 15;
        #pragma unroll
        for (int h = 0; h < 4; ++h) {
            int rr = row0 + h * 16;
            int idx = rowIdx[rr];
            long g = g0 + rr;
            const float4* qp  = (const float4*)(q    + g * CDIM + c8 * 8);
            const float4* kp2 = (const float4*)(keys + (long)idx * CDIM + c8 * 8);
            const float4* rp  = (const float4*)(rep  + g * CDIM + c8 * 8);
            const float4* vp  = (const float4*)(vals + (long)idx * CDIM + c8 * 8);
            float kg = 0.f, vg = 0.f;
            #pragma unroll
            for (int hh = 0; hh < 2; ++hh) {
                float4 qa = qp[hh], ka = kp2[hh], ra = rp[hh], va = vp[hh];
                float d0 = qa.x - ka.x, d1 = qa.y - ka.y, d2 = qa.z - ka.z, d3 = qa.w - ka.w;
                kg += d0*d0 + d1*d1 + d2*d2 + d3*d3;
                float e0 = ra.x - va.x, e1 = ra.y - va.y, e2 = ra.z - va.z, e3 = ra.w - va.w;
                vg += e0*e0 + e1*e1 + e2*e2 + e3*e3;
            }
            kgp[rr][c8] = kg; vgp[rr][c8] = vg;
        }
    }
    __syncthreads();
    if (t < T_ROWS) {
        float a = 0.f, b = 0.f;
        for (int j = 0; j < 16; ++j) { a += kgp[t][j]; b += vgp[t][j]; }
        long g = g0 + t;
        out[g] = a;
        out[NROWS + g] = b;
    }
}

extern "C" void kernel_launch(void* const* d_in, const int* in_sizes, int n_in,
                              void* d_out, int out_size, void* d_ws, size_t ws_size,
                              hipStream_t stream) {
    const float* q    = (const float*)d_in[0];  // trend_representation
    const float* rep  = (const float*)d_in[1];  // representation
    const float* keys = (const float*)d_in[2];
    const float* vals = (const float*)d_in[3];
    _Float16* kh = (_Float16*)d_ws;             // 256 KB fp16 key cache (fragment order)

    cvt_keys_kernel<<<128, 256, 0, stream>>>(keys, kh);
    gather_main<<<NROWS / T_ROWS, 256, 0, stream>>>(q, rep, keys, vals, kh,
                                                    (float*)d_out);
}